// Round 7
// baseline (104.360 us; speedup 1.0000x reference)
//
#include <hip/hip_runtime.h>

#define E_ 8
#define R_ 64
#define D_ 2048
#define BS_ 16384
#define SEG 64                               // int offset of per-expert segment lists
#define WS_ABF_OFF (1ull<<20)                // bf16 A (2MB) then B (2MB) at 1 MB
#define WS_NEED_FULL (WS_ABF_OFF + 4ull*1024*1024)

typedef __attribute__((ext_vector_type(8))) short short8;
typedef __attribute__((ext_vector_type(4))) short short4v;
typedef __attribute__((ext_vector_type(4))) float f32x4;

__device__ __forceinline__ unsigned short f2bf(float f){
  unsigned u = __float_as_uint(f);
  u += 0x7fffu + ((u >> 16) & 1u);           // RNE
  return (unsigned short)(u >> 16);
}
__device__ __forceinline__ short8 pack8(f32x4 a, f32x4 b){
  short8 r;
  r[0]=(short)f2bf(a[0]); r[1]=(short)f2bf(a[1]); r[2]=(short)f2bf(a[2]); r[3]=(short)f2bf(a[3]);
  r[4]=(short)f2bf(b[0]); r[5]=(short)f2bf(b[1]); r[6]=(short)f2bf(b[2]); r[7]=(short)f2bf(b[3]);
  return r;
}
// async global->LDS DMA, 16B/lane. LDS dest = wave-uniform base + lane*16
// (linear); global src is PER-LANE (swizzle folded there). Counts in vmcnt;
// __syncthreads()'s implied vmcnt(0) is the completion wait (proven).
__device__ __forceinline__ void gload16(const void* g, void* l){
  __builtin_amdgcn_global_load_lds(
      (const __attribute__((address_space(1))) void*)g,
      (__attribute__((address_space(3))) void*)l, 16, 0, 0);
}

// ---- prologue: scatter (blocks 0..63) + A,B fp32->bf16 conv (2048 blocks) ----
// ws ints: [0..8) cursors (end = counts) | [SEG + e*BS_ ...) token lists
__global__ void scatter_conv(const int* __restrict__ tidx, int* __restrict__ ws,
                             const float* __restrict__ Am, const float* __restrict__ Bm,
                             unsigned short* __restrict__ Abf){
  if (blockIdx.x >= 64){
    const int i = (blockIdx.x - 64)*256 + threadIdx.x;     // 4 elems each, 2M total
    const f32x4 v = (i < 262144) ? *(const f32x4*)(Am + (size_t)i*4)
                                 : *(const f32x4*)(Bm + (size_t)(i - 262144)*4);
    short4v a;
    a[0]=(short)f2bf(v[0]); a[1]=(short)f2bf(v[1]); a[2]=(short)f2bf(v[2]); a[3]=(short)f2bf(v[3]);
    *(short4v*)(Abf + (size_t)i*4) = a;                    // Bbf contiguous after Abf
    return;
  }
  __shared__ int lh[E_], lbase[E_], lrank[E_];
  const int t = threadIdx.x;
  if (t < E_){ lh[t] = 0; lrank[t] = 0; }
  __syncthreads();
  const int tok = blockIdx.x*256 + t;
  const int e = tidx[tok];
  atomicAdd(&lh[e], 1);
  __syncthreads();
  if (t < E_) lbase[t] = atomicAdd(&ws[t], lh[t]);   // device-scope
  __syncthreads();
  const int r = atomicAdd(&lrank[e], 1);
  ws[SEG + e*BS_ + lbase[e] + r] = tok;
}

// ---------------- Fused: out[tok] = B_e (A_e x[tok]) ----------------
// R0's proven single-buffered 2-barrier structure with COARSER PHASES:
// phase 1 = 8 chunks of BK=256 floats (was 16 x BK=128); phase 2 = 4 B-tiles
// of 512 out-cols (was 8 x 256). 24 -> 12 vmcnt(0) drains per block, with
// IDENTICAL total staged bytes, swizzle math, fragment mapping, and stores.
// LDS 68K (ph1: x32K|A32K|H4K ; ph2: B64K|H4K) -> 2 blocks/CU (R6 proved
// occupancy beyond 2/CU is not the limiter here).
__global__ __launch_bounds__(256) void fused(
    const float* __restrict__ x, const unsigned short* __restrict__ Abf,
    const int* __restrict__ ws, float* __restrict__ out)
{
  const int e    = blockIdx.x & 7;
  const int tile = blockIdx.x >> 3;
  const int cnt  = ws[e];
  const int start = tile * 32;
  if (start >= cnt) return;
  const int valid = (cnt - start < 32) ? (cnt - start) : 32;
  const int* seg = ws + SEG + e*BS_;

  __shared__ int tokIds[32];
  __shared__ __align__(16) char smem[69632];   // ph1: x32K|A32K|H4K ; ph2: B64K|H4K

  const int tid = threadIdx.x;
  if (tid < 32) tokIds[tid] = seg[start + (tid < valid ? tid : valid-1)];
  __syncthreads();

  const int lane = tid & 63, w = tid >> 6;     // 4 waves
  // ---- phase-1 staging sources (per-lane, swizzle pre-folded) ----
  // x: 32 rows, 1KB/chunk each -> 1 row per instr, 8 instr/wave.
  // A: 64 rows, 512B/chunk each -> 2 rows per instr, 8 instr/wave.
  const char* xsrc[8]; const char* asrc[8];
  #pragma unroll
  for (int i = 0; i < 8; ++i){
    const int xrow = w*8 + i;                          // 0..31
    xsrc[i] = (const char*)(x + (size_t)tokIds[xrow]*D_)
              + ((lane*16) ^ ((xrow & 7) << 4));
    const int arow = (w*8 + i)*2 + (lane >> 5);        // 0..63
    asrc[i] = (const char*)(Abf + ((size_t)e*R_ + arow)*D_)
              + (((lane & 31)*16) ^ ((arow & 7) << 4));
  }
  char* const xdst = smem;            // 32 KB, row r at r*1024
  char* const adst = smem + 32768;    // 32 KB, row r at r*512
  char* const pH   = smem + 65536;    //  4 KB

  const int llo = lane & 15, lhi = lane >> 4;
  const int tw = w & 1, rw = w >> 1;
  const int xrow_c = tw*16 + llo;            // 0..31
  const int arow0  = rw*32 + llo;            // and +16
  const int sw     = (llo & 7) << 4;         // == (xrow_c&7)<<4 == (arow0&7)<<4
  f32x4 acc0={0.f,0.f,0.f,0.f}, acc1={0.f,0.f,0.f,0.f};

  for (int c = 0; c < 8; ++c){               // BK = 256 floats
    #pragma unroll
    for (int i = 0; i < 8; ++i){
      gload16(xsrc[i] + c*1024, xdst + (w*8+i)*1024);
      gload16(asrc[i] + c*512,  adst + (w*8+i)*1024);
    }
    __syncthreads();                         // chunk landed (implied vmcnt(0))
    #pragma unroll
    for (int kk = 0; kk < 8; ++kk){
      const f32x4 v0 = *(const f32x4*)(xdst + xrow_c*1024 + ((kk*128 + lhi*32) ^ sw));
      const f32x4 v1 = *(const f32x4*)(xdst + xrow_c*1024 + ((kk*128 + lhi*32 + 16) ^ sw));
      const short8 af = pack8(v0, v1);
      const short8 b0 = *(const short8*)(adst + arow0*512 + ((kk*64 + lhi*16) ^ sw));
      const short8 b1 = *(const short8*)(adst + (arow0+16)*512 + ((kk*64 + lhi*16) ^ sw));
      acc0 = __builtin_amdgcn_mfma_f32_16x16x32_bf16(af, b0, acc0, 0,0,0);
      acc1 = __builtin_amdgcn_mfma_f32_16x16x32_bf16(af, b1, acc1, 0,0,0);
    }
    __syncthreads();                         // reads done before next DMA lands
  }

  // ---- H -> LDS (bf16, swizzled). C/D layout: row=(lane>>4)*4+i, col=llo ----
  #pragma unroll
  for (int i = 0; i < 4; ++i){
    const int hr = tw*16 + lhi*4 + i;
    const int hsw = (hr & 7) << 4;
    *(unsigned short*)(pH + ((hr*128 + (rw*32+llo)*2)    ^ hsw)) = f2bf(acc0[i]);
    *(unsigned short*)(pH + ((hr*128 + (rw*32+16+llo)*2) ^ hsw)) = f2bf(acc1[i]);
  }
  __syncthreads();

  // ---- phase 2: H-frags + per-cg2 512-col B tiles (64KB, 16 instr/wave) ----
  short8 aH[2][2];
  #pragma unroll
  for (int g = 0; g < 2; ++g){
    const int r_ = g*16 + llo;               // (r_&7) == (llo&7)
    aH[g][0] = *(const short8*)(pH + ((r_*128 + lhi*16) ^ sw));
    aH[g][1] = *(const short8*)(pH + ((r_*128 + 64 + lhi*16) ^ sw));
  }

  unsigned vmask = 0;
  int rowOff[2][4];
  #pragma unroll
  for (int g = 0; g < 2; ++g){
    #pragma unroll
    for (int i = 0; i < 4; ++i){
      const int r_ = g*16 + lhi*4 + i;
      if (r_ < valid) vmask |= 1u << (g*4 + i);
      rowOff[g][i] = tokIds[r_ < valid ? r_ : 0]*D_ + llo;
    }
  }

  const unsigned short* Bbf = Abf + E_*R_*D_;
  // per instr j=w*16+i2: 8 B-rows (128B each); row = j*8 + (lane>>3)
  const char* bsrc = (const char*)Bbf + (size_t)e*D_*R_*2
                     + (size_t)(w*128 + (lane >> 3))*128
                     + (((lane & 7)*16) ^ (((lane >> 3) & 7) << 4));
  char* const pB = smem;                       // 64 KB, row r at r*128

  for (int cg2 = 0; cg2 < 4; ++cg2){
    #pragma unroll
    for (int i2 = 0; i2 < 16; ++i2)
      gload16(bsrc + cg2*65536 + i2*1024, pB + (w*16+i2)*1024);
    __syncthreads();                         // B tile landed
    #pragma unroll
    for (int nt = 0; nt < 8; ++nt){
      const int rowL = w*128 + nt*16 + llo;  // (rowL&7) == (llo&7)
      const short8 b0 = *(const short8*)(pB + ((rowL*128 + lhi*16) ^ sw));
      const short8 b1 = *(const short8*)(pB + ((rowL*128 + 64 + lhi*16) ^ sw));
      f32x4 o0 = {0.f,0.f,0.f,0.f}, o1 = {0.f,0.f,0.f,0.f};
      o0 = __builtin_amdgcn_mfma_f32_16x16x32_bf16(aH[0][0], b0, o0, 0,0,0);
      o0 = __builtin_amdgcn_mfma_f32_16x16x32_bf16(aH[0][1], b1, o0, 0,0,0);
      o1 = __builtin_amdgcn_mfma_f32_16x16x32_bf16(aH[1][0], b0, o1, 0,0,0);
      o1 = __builtin_amdgcn_mfma_f32_16x16x32_bf16(aH[1][1], b1, o1, 0,0,0);
      const int col = cg2*512 + w*128 + nt*16;
      #pragma unroll
      for (int i = 0; i < 4; ++i){
        if (vmask & (1u <<  i))    __builtin_nontemporal_store(o0[i], &out[rowOff[0][i] + col]);
        if (vmask & (1u << (4+i))) __builtin_nontemporal_store(o1[i], &out[rowOff[1][i] + col]);
      }
    }
    __syncthreads();                         // reads done before next B DMA
  }
}

// ---------------- correctness-only fallback (tiny ws): exact fp32 ----------------
__global__ __launch_bounds__(256) void naive_kernel(
    const float* __restrict__ x, const float* __restrict__ Am,
    const float* __restrict__ Bm, const int* __restrict__ tidx,
    float* __restrict__ out)
{
  const int tok = blockIdx.x;
  const int e = tidx[tok];
  __shared__ float xs[D_];
  __shared__ float h[R_];
  const int tid = threadIdx.x;
  for (int i = tid; i < D_; i += 256) xs[i] = x[(size_t)tok*D_ + i];
  __syncthreads();
  if (tid < R_){
    float s = 0.f;
    const float* ar = Am + ((size_t)e*R_ + tid)*D_;
    for (int d = 0; d < D_; ++d) s += xs[d]*ar[d];
    h[tid] = s;
  }
  __syncthreads();
  for (int c = tid; c < D_; c += 256){
    float s = 0.f;
    const float* br = Bm + ((size_t)e*D_ + c)*R_;
    #pragma unroll
    for (int r = 0; r < R_; ++r) s += h[r]*br[r];
    out[(size_t)tok*D_ + c] = s;
  }
}

extern "C" void kernel_launch(void* const* d_in, const int* in_sizes, int n_in,
                              void* d_out, int out_size, void* d_ws, size_t ws_size,
                              hipStream_t stream){
  const float* x    = (const float*)d_in[0];
  const float* Am   = (const float*)d_in[1];
  const float* Bm   = (const float*)d_in[2];
  const int*   tidx = (const int*)d_in[3];
  float* out = (float*)d_out;
  int*   ws  = (int*)d_ws;
  unsigned short* Abf = (unsigned short*)((char*)d_ws + WS_ABF_OFF);

  if (ws_size >= WS_NEED_FULL){
    hipMemsetAsync(d_ws, 0, 32, stream);                    // zero 8 cursors
    scatter_conv<<<64 + 2048, 256, 0, stream>>>(tidx, ws, Am, Bm, Abf);
    fused<<<8*(BS_/32), 256, 0, stream>>>(x, Abf, ws, out);
  } else {
    naive_kernel<<<BS_, 256, 0, stream>>>(x, Am, Bm, tidx, out);
  }
}

// Round 8
// 84.443 us; speedup vs baseline: 1.2359x; 1.2359x over previous
//
#include <hip/hip_runtime.h>

#define E_ 8
#define R_ 64
#define D_ 2048
#define BS_ 16384
#define SEG 64                               // int offset of per-expert segment lists
#define WS_ABF_OFF (1ull<<20)                // bf16 A (2MB) then B (2MB) at 1 MB
#define WS_NEED_FULL (WS_ABF_OFF + 4ull*1024*1024)

typedef __attribute__((ext_vector_type(8))) short short8;
typedef __attribute__((ext_vector_type(4))) short short4v;
typedef __attribute__((ext_vector_type(4))) float f32x4;

__device__ __forceinline__ unsigned short f2bf(float f){
  unsigned u = __float_as_uint(f);
  u += 0x7fffu + ((u >> 16) & 1u);           // RNE
  return (unsigned short)(u >> 16);
}
__device__ __forceinline__ short8 pack8(f32x4 a, f32x4 b){
  short8 r;
  r[0]=(short)f2bf(a[0]); r[1]=(short)f2bf(a[1]); r[2]=(short)f2bf(a[2]); r[3]=(short)f2bf(a[3]);
  r[4]=(short)f2bf(b[0]); r[5]=(short)f2bf(b[1]); r[6]=(short)f2bf(b[2]); r[7]=(short)f2bf(b[3]);
  return r;
}
// async global->LDS DMA, 16B/lane. LDS dest = wave-uniform base + lane*16
// (linear); global src is PER-LANE (swizzle folded there). Counts in vmcnt;
// __syncthreads()'s implied vmcnt(0) is the completion wait (proven).
__device__ __forceinline__ void gload16(const void* g, void* l){
  __builtin_amdgcn_global_load_lds(
      (const __attribute__((address_space(1))) void*)g,
      (__attribute__((address_space(3))) void*)l, 16, 0, 0);
}

// ---- prologue: scatter (blocks 0..63) + A,B fp32->bf16 conv (2048 blocks) ----
// ws ints: [0..8) cursors (end = counts) | [SEG + e*BS_ ...) token lists
__global__ void scatter_conv(const int* __restrict__ tidx, int* __restrict__ ws,
                             const float* __restrict__ Am, const float* __restrict__ Bm,
                             unsigned short* __restrict__ Abf){
  if (blockIdx.x >= 64){
    const int i = (blockIdx.x - 64)*256 + threadIdx.x;     // 4 elems each, 2M total
    const f32x4 v = (i < 262144) ? *(const f32x4*)(Am + (size_t)i*4)
                                 : *(const f32x4*)(Bm + (size_t)(i - 262144)*4);
    short4v a;
    a[0]=(short)f2bf(v[0]); a[1]=(short)f2bf(v[1]); a[2]=(short)f2bf(v[2]); a[3]=(short)f2bf(v[3]);
    *(short4v*)(Abf + (size_t)i*4) = a;                    // Bbf contiguous after Abf
    return;
  }
  __shared__ int lh[E_], lbase[E_], lrank[E_];
  const int t = threadIdx.x;
  if (t < E_){ lh[t] = 0; lrank[t] = 0; }
  __syncthreads();
  const int tok = blockIdx.x*256 + t;
  const int e = tidx[tok];
  atomicAdd(&lh[e], 1);
  __syncthreads();
  if (t < E_) lbase[t] = atomicAdd(&ws[t], lh[t]);   // device-scope
  __syncthreads();
  const int r = atomicAdd(&lrank[e], 1);
  ws[SEG + e*BS_ + lbase[e] + r] = tok;
}

// ---------------- Fused: out[tok] = B_e (A_e x[tok]) ----------------
// Phase 1 = R0's proven staged 32tok x 64r loop (single-buffered, 16 chunks,
// 2 barriers each) — byte-identical. Phase 2 REPLACED: B-fragments load
// DIRECT from global. B_e is 256 KB and all blocks of expert e land on XCD e
// (e == blockIdx&7, XCD = blockIdx%8 round-robin) -> B_e is hot in that XCD's
// private L2. This deletes 8 of 24 vmcnt(0) drain-phases, 256 KB/block of LDS
// round-trip, and every phase-2 barrier; the 8 independent loads per cg
// pipeline freely against the 16 MFMAs (no compiler-defeating fences needed).
// Indexing for direct B-frags was correctness-verified in the R5 kernel.
__global__ __launch_bounds__(256) void fused(
    const float* __restrict__ x, const unsigned short* __restrict__ Abf,
    const int* __restrict__ ws, float* __restrict__ out)
{
  const int e    = blockIdx.x & 7;
  const int tile = blockIdx.x >> 3;
  const int cnt  = ws[e];
  const int start = tile * 32;
  if (start >= cnt) return;
  const int valid = (cnt - start < 32) ? (cnt - start) : 32;
  const int* seg = ws + SEG + e*BS_;

  __shared__ int tokIds[32];
  __shared__ __align__(16) char smem[36864];   // x16K | A16K | H4K

  const int tid = threadIdx.x;
  if (tid < 32) tokIds[tid] = seg[start + (tid < valid ? tid : valid-1)];
  __syncthreads();

  const int lane = tid & 63, w = tid >> 6;     // 4 waves
  // ---- phase-1 staging sources (per-lane, swizzle pre-folded) ----
  const char* xsrc[4]; const char* asrc[4];
  #pragma unroll
  for (int i = 0; i < 4; ++i){
    const int gi = w*4 + i;
    const int xrow = gi*2 + (lane >> 5);               // 2 rows per 1KB instr
    xsrc[i] = (const char*)(x + (size_t)tokIds[xrow]*D_)
              + (((lane & 31)*16) ^ ((xrow & 7) << 4));
    const int arow = gi*4 + (lane >> 4);               // 4 rows per 1KB instr
    asrc[i] = (const char*)(Abf + ((size_t)e*R_ + arow)*D_)
              + (((lane & 15)*16) ^ ((arow & 7) << 4));
  }
  char* const xdst = smem;            // 16 KB
  char* const adst = smem + 16384;    // 16 KB
  char* const pH   = smem + 32768;    //  4 KB

  const int llo = lane & 15, lhi = lane >> 4;
  const int tw = w & 1, rw = w >> 1;
  const int xrow_c = tw*16 + llo;            // 0..31
  const int arow0  = rw*32 + llo;            // and +16
  const int sw     = (llo & 7) << 4;         // == (xrow_c&7)<<4 == (arow0&7)<<4
  f32x4 acc0={0.f,0.f,0.f,0.f}, acc1={0.f,0.f,0.f,0.f};

  for (int c = 0; c < 16; ++c){
    #pragma unroll
    for (int i = 0; i < 4; ++i){
      gload16(xsrc[i] + c*512, xdst + (w*4+i)*1024);
      gload16(asrc[i] + c*256, adst + (w*4+i)*1024);
    }
    __syncthreads();                         // chunk c landed
    #pragma unroll
    for (int kk = 0; kk < 4; ++kk){
      const f32x4 v0 = *(const f32x4*)(xdst + xrow_c*512 + ((kk*128 + lhi*32) ^ sw));
      const f32x4 v1 = *(const f32x4*)(xdst + xrow_c*512 + ((kk*128 + lhi*32 + 16) ^ sw));
      const short8 af = pack8(v0, v1);
      const short8 b0 = *(const short8*)(adst + arow0*256 + ((kk*64 + lhi*16) ^ sw));
      const short8 b1 = *(const short8*)(adst + (arow0+16)*256 + ((kk*64 + lhi*16) ^ sw));
      acc0 = __builtin_amdgcn_mfma_f32_16x16x32_bf16(af, b0, acc0, 0,0,0);
      acc1 = __builtin_amdgcn_mfma_f32_16x16x32_bf16(af, b1, acc1, 0,0,0);
    }
    __syncthreads();                         // reads done before next DMA lands
  }

  // ---- H -> LDS (bf16, swizzled). C/D layout: row=(lane>>4)*4+i, col=llo ----
  #pragma unroll
  for (int i = 0; i < 4; ++i){
    const int hr = tw*16 + lhi*4 + i;
    const int hsw = (hr & 7) << 4;
    *(unsigned short*)(pH + ((hr*128 + (rw*32+llo)*2)    ^ hsw)) = f2bf(acc0[i]);
    *(unsigned short*)(pH + ((hr*128 + (rw*32+16+llo)*2) ^ hsw)) = f2bf(acc1[i]);
  }
  __syncthreads();

  // ---- H A-frags (verified): m=llo(token in group g), k(r)=lhi*8 ----
  short8 aH[2][2];
  #pragma unroll
  for (int g = 0; g < 2; ++g){
    const int r_ = g*16 + llo;               // (r_&7) == (llo&7)
    aH[g][0] = *(const short8*)(pH + ((r_*128 + lhi*16) ^ sw));
    aH[g][1] = *(const short8*)(pH + ((r_*128 + 64 + lhi*16) ^ sw));
  }

  unsigned vmask = 0;
  int rowOff[2][4];
  #pragma unroll
  for (int g = 0; g < 2; ++g){
    #pragma unroll
    for (int i = 0; i < 4; ++i){
      const int r_ = g*16 + lhi*4 + i;
      if (r_ < valid) vmask |= 1u << (g*4 + i);
      rowOff[g][i] = tokIds[r_ < valid ? r_ : 0]*D_ + llo;
    }
  }

  // ---- phase 2: B direct from (same-XCD) L2; no LDS, no barriers ----
  // B-frag (R5-verified): n=llo -> out-col col+llo, k=lhi*8; b1 = r 32..63.
  // Per cg: 8 independent 16B-lane loads batched ahead of 16 MFMAs.
  const unsigned short* Bbf = Abf + E_*R_*D_;
  const unsigned short* pb = Bbf + (size_t)e*D_*R_
                             + (size_t)(w*64 + llo)*R_ + lhi*8;
  #pragma unroll 2
  for (int cg = 0; cg < 8; ++cg){
    const unsigned short* pbc = pb + (size_t)cg*256*R_;
    short8 b0[4], b1[4];
    #pragma unroll
    for (int nt = 0; nt < 4; ++nt){
      b0[nt] = *(const short8*)(pbc + nt*16*R_);
      b1[nt] = *(const short8*)(pbc + nt*16*R_ + 32);
    }
    #pragma unroll
    for (int nt = 0; nt < 4; ++nt){
      f32x4 o0 = {0.f,0.f,0.f,0.f}, o1 = {0.f,0.f,0.f,0.f};
      o0 = __builtin_amdgcn_mfma_f32_16x16x32_bf16(aH[0][0], b0[nt], o0, 0,0,0);
      o0 = __builtin_amdgcn_mfma_f32_16x16x32_bf16(aH[0][1], b1[nt], o0, 0,0,0);
      o1 = __builtin_amdgcn_mfma_f32_16x16x32_bf16(aH[1][0], b0[nt], o1, 0,0,0);
      o1 = __builtin_amdgcn_mfma_f32_16x16x32_bf16(aH[1][1], b1[nt], o1, 0,0,0);
      const int col = cg*256 + w*64 + nt*16;
      #pragma unroll
      for (int i = 0; i < 4; ++i){
        if (vmask & (1u <<  i))    __builtin_nontemporal_store(o0[i], &out[rowOff[0][i] + col]);
        if (vmask & (1u << (4+i))) __builtin_nontemporal_store(o1[i], &out[rowOff[1][i] + col]);
      }
    }
  }
}

// ---------------- correctness-only fallback (tiny ws): exact fp32 ----------------
__global__ __launch_bounds__(256) void naive_kernel(
    const float* __restrict__ x, const float* __restrict__ Am,
    const float* __restrict__ Bm, const int* __restrict__ tidx,
    float* __restrict__ out)
{
  const int tok = blockIdx.x;
  const int e = tidx[tok];
  __shared__ float xs[D_];
  __shared__ float h[R_];
  const int tid = threadIdx.x;
  for (int i = tid; i < D_; i += 256) xs[i] = x[(size_t)tok*D_ + i];
  __syncthreads();
  if (tid < R_){
    float s = 0.f;
    const float* ar = Am + ((size_t)e*R_ + tid)*D_;
    for (int d = 0; d < D_; ++d) s += xs[d]*ar[d];
    h[tid] = s;
  }
  __syncthreads();
  for (int c = tid; c < D_; c += 256){
    float s = 0.f;
    const float* br = Bm + ((size_t)e*D_ + c)*R_;
    #pragma unroll
    for (int r = 0; r < R_; ++r) s += h[r]*br[r];
    out[(size_t)tok*D_ + c] = s;
  }
}

extern "C" void kernel_launch(void* const* d_in, const int* in_sizes, int n_in,
                              void* d_out, int out_size, void* d_ws, size_t ws_size,
                              hipStream_t stream){
  const float* x    = (const float*)d_in[0];
  const float* Am   = (const float*)d_in[1];
  const float* Bm   = (const float*)d_in[2];
  const int*   tidx = (const int*)d_in[3];
  float* out = (float*)d_out;
  int*   ws  = (int*)d_ws;
  unsigned short* Abf = (unsigned short*)((char*)d_ws + WS_ABF_OFF);

  if (ws_size >= WS_NEED_FULL){
    hipMemsetAsync(d_ws, 0, 32, stream);                    // zero 8 cursors
    scatter_conv<<<64 + 2048, 256, 0, stream>>>(tidx, ws, Am, Bm, Abf);
    fused<<<8*(BS_/32), 256, 0, stream>>>(x, Abf, ws, out);
  } else {
    naive_kernel<<<BS_, 256, 0, stream>>>(x, Am, Bm, tidx, out);
  }
}